// Round 1
// baseline (925.846 us; speedup 1.0000x reference)
//
#include <hip/hip_runtime.h>
#include <hip/hip_bf16.h>
#include <math.h>

#define NN 50000
#define NE 800000
#define C  128

// ---------------- CSR build ----------------

__global__ void k_zero(int* __restrict__ p, int n) {
    int i = blockIdx.x * blockDim.x + threadIdx.x;
    if (i < n) p[i] = 0;
}

__global__ void k_hist(const int* __restrict__ dst, int* __restrict__ deg, int nE) {
    int e = blockIdx.x * blockDim.x + threadIdx.x;
    if (e < nE) atomicAdd(&deg[dst[e]], 1);
}

// single-block scan: rowptr[0]=0, rowptr[i+1] = sum deg[0..i]
__global__ void k_scan(const int* __restrict__ deg, int* __restrict__ rowptr, int n) {
    __shared__ int wsum[16];
    __shared__ int carry;
    int tid  = threadIdx.x;
    int lane = tid & 63, wid = tid >> 6;
    if (tid == 0) { rowptr[0] = 0; carry = 0; }
    __syncthreads();
    for (int base = 0; base < n; base += 1024) {
        int i = base + tid;
        int v = (i < n) ? deg[i] : 0;
        int incl = v;
        #pragma unroll
        for (int d = 1; d < 64; d <<= 1) {
            int t = __shfl_up(incl, d, 64);
            if (lane >= d) incl += t;
        }
        if (lane == 63) wsum[wid] = incl;
        __syncthreads();
        int wo = 0, total = 0;
        #pragma unroll
        for (int w = 0; w < 16; ++w) {
            int s = wsum[w];
            if (w < wid) wo += s;
            total += s;
        }
        if (i < n) rowptr[i + 1] = carry + wo + incl;
        __syncthreads();
        if (tid == 0) carry += total;
        __syncthreads();
    }
}

__global__ void k_fill(const int* __restrict__ src, const int* __restrict__ dst,
                       const int* __restrict__ rowptr, int* __restrict__ cursor,
                       int* __restrict__ esrc, int nE) {
    int e = blockIdx.x * blockDim.x + threadIdx.x;
    if (e < nE) {
        int d   = dst[e];
        int pos = rowptr[d] + atomicAdd(&cursor[d], 1);
        esrc[pos] = src[e];
    }
}

// ---------------- segment max (aggregation) ----------------
// 2 nodes per block (256 threads), thread = channel. Order-independent (max),
// so CSR fill nondeterminism doesn't affect the result.
__global__ void k_segmax(const float* __restrict__ h, const int* __restrict__ rowptr,
                         const int* __restrict__ esrc, float* __restrict__ agg, int n) {
    int node = blockIdx.x * 2 + (threadIdx.x >> 7);
    int c    = threadIdx.x & 127;
    if (node >= n) return;
    int beg = rowptr[node], end = rowptr[node + 1];
    float m = -INFINITY;
    int i = beg;
    for (; i + 3 < end; i += 4) {
        int s0 = esrc[i], s1 = esrc[i + 1], s2 = esrc[i + 2], s3 = esrc[i + 3];
        float v0 = h[s0 * C + c], v1 = h[s1 * C + c];
        float v2 = h[s2 * C + c], v3 = h[s3 * C + c];
        m = fmaxf(m, fmaxf(fmaxf(v0, v1), fmaxf(v2, v3)));
    }
    for (; i < end; ++i) m = fmaxf(m, h[esrc[i] * C + c]);
    // empty segment -> -inf -> 0 per isfinite() rule
    agg[node * C + c] = (end > beg) ? m : 0.0f;
}

// ---------------- fused SAGE gemm: out = relu?(agg@Wl^T + x@Wr^T + b) ---------
// 64 threads/block, 8 nodes/block, each thread owns outputs o and o+64.
template<int RELU>
__global__ __launch_bounds__(64) void k_gemm(
        const float* __restrict__ A, const float* __restrict__ X,
        const float* __restrict__ Wl, const float* __restrict__ Wr,
        const float* __restrict__ bias, float* __restrict__ out, int n) {
    __shared__ float As[8][C];
    __shared__ float Xs[8][C];
    int tid = threadIdx.x;
    int n0  = blockIdx.x * 8;
    #pragma unroll
    for (int r = 0; r < 8; ++r) {
        As[r][tid]      = A[(n0 + r) * C + tid];
        As[r][tid + 64] = A[(n0 + r) * C + tid + 64];
        Xs[r][tid]      = X[(n0 + r) * C + tid];
        Xs[r][tid + 64] = X[(n0 + r) * C + tid + 64];
    }
    __syncthreads();
    int o1 = tid, o2 = tid + 64;
    float acc1[8], acc2[8];
    float b1 = bias[o1], b2 = bias[o2];
    #pragma unroll
    for (int m = 0; m < 8; ++m) { acc1[m] = b1; acc2[m] = b2; }

    const float* wl1 = &Wl[o1 * C];
    const float* wl2 = &Wl[o2 * C];
    #pragma unroll 4
    for (int k = 0; k < C; k += 4) {
        float4 w1 = *(const float4*)(wl1 + k);
        float4 w2 = *(const float4*)(wl2 + k);
        #pragma unroll
        for (int m = 0; m < 8; ++m) {
            float4 a = *(const float4*)(&As[m][k]);
            acc1[m] += a.x * w1.x + a.y * w1.y + a.z * w1.z + a.w * w1.w;
            acc2[m] += a.x * w2.x + a.y * w2.y + a.z * w2.z + a.w * w2.w;
        }
    }
    const float* wr1 = &Wr[o1 * C];
    const float* wr2 = &Wr[o2 * C];
    #pragma unroll 4
    for (int k = 0; k < C; k += 4) {
        float4 w1 = *(const float4*)(wr1 + k);
        float4 w2 = *(const float4*)(wr2 + k);
        #pragma unroll
        for (int m = 0; m < 8; ++m) {
            float4 a = *(const float4*)(&Xs[m][k]);
            acc1[m] += a.x * w1.x + a.y * w1.y + a.z * w1.z + a.w * w1.w;
            acc2[m] += a.x * w2.x + a.y * w2.y + a.z * w2.z + a.w * w2.w;
        }
    }
    #pragma unroll
    for (int m = 0; m < 8; ++m) {
        float v1 = acc1[m], v2 = acc2[m];
        if (RELU) { v1 = fmaxf(v1, 0.f); v2 = fmaxf(v2, 0.f); }
        out[(n0 + m) * C + o1] = v1;
        out[(n0 + m) * C + o2] = v2;
    }
}

// ---------------- final 128->1 head: out[i] = h[i]·w + b ----------------
__global__ void k_gemv(const float* __restrict__ h, const float* __restrict__ w,
                       const float* __restrict__ b, float* __restrict__ out, int n) {
    int node = blockIdx.x * (blockDim.x >> 6) + (threadIdx.x >> 6);
    int lane = threadIdx.x & 63;
    if (node >= n) return;
    float s = h[node * C + lane] * w[lane] + h[node * C + 64 + lane] * w[64 + lane];
    #pragma unroll
    for (int d = 32; d > 0; d >>= 1) s += __shfl_down(s, d, 64);
    if (lane == 0) out[node] = s + b[0];
}

// ---------------- launch ----------------

extern "C" void kernel_launch(void* const* d_in, const int* in_sizes, int n_in,
                              void* d_out, int out_size, void* d_ws, size_t ws_size,
                              hipStream_t stream) {
    const float* x     = (const float*)d_in[0];
    const int*   ei    = (const int*)d_in[1];
    const int*   src   = ei;          // edge_index[0]
    const int*   dstp  = ei + NE;     // edge_index[1]
    const float* sWl   = (const float*)d_in[2];
    const float* sB    = (const float*)d_in[3];
    const float* sWr   = (const float*)d_in[4];
    const float* rt1Wl = (const float*)d_in[5];
    const float* rt1B  = (const float*)d_in[6];
    const float* rt1Wr = (const float*)d_in[7];
    const float* rt2Wl = (const float*)d_in[8];
    const float* rt2B  = (const float*)d_in[9];
    const float* rt2Wr = (const float*)d_in[10];
    const float* rt3W  = (const float*)d_in[11];
    const float* rt3B  = (const float*)d_in[12];
    const float* mv1Wl = (const float*)d_in[13];
    const float* mv1B  = (const float*)d_in[14];
    const float* mv1Wr = (const float*)d_in[15];
    const float* mv2Wl = (const float*)d_in[16];
    const float* mv2B  = (const float*)d_in[17];
    const float* mv2Wr = (const float*)d_in[18];
    const float* mv3W  = (const float*)d_in[19];
    const float* mv3B  = (const float*)d_in[20];
    float* out = (float*)d_out;

    // workspace layout (needs ~106 MB)
    char* ws = (char*)d_ws;
    int* rowptr = (int*)ws;                 // NN+1
    int* cursor = rowptr + (NN + 1);        // NN (deg, then fill cursor)
    int* esrc   = cursor + NN;              // NE
    size_t off  = (((size_t)(NN + 1 + NN + NE) * 4) + 255) & ~(size_t)255;
    float* bufA = (float*)(ws + off);       // agg scratch
    float* buf1 = bufA + (size_t)NN * C;    // mv, later rt2-out
    float* buf2 = buf1 + (size_t)NN * C;    // rt, later md2-out
    float* buf3 = buf2 + (size_t)NN * C;    // md

    const int TB = 256;
    // CSR build
    k_zero<<<(NN + TB - 1) / TB, TB, 0, stream>>>(cursor, NN);
    k_hist<<<(NE + TB - 1) / TB, TB, 0, stream>>>(dstp, cursor, NE);
    k_scan<<<1, 1024, 0, stream>>>(cursor, rowptr, NN);
    k_zero<<<(NN + TB - 1) / TB, TB, 0, stream>>>(cursor, NN);
    k_fill<<<(NE + TB - 1) / TB, TB, 0, stream>>>(src, dstp, rowptr, cursor, esrc, NE);

    dim3 gSeg(NN / 2), bSeg(256);
    dim3 gGem(NN / 8), bGem(64);

    // layer shared: mv = relu(sage(x))
    k_segmax<<<gSeg, bSeg, 0, stream>>>(x, rowptr, esrc, bufA, NN);
    k_gemm<1><<<gGem, bGem, 0, stream>>>(bufA, x, sWl, sWr, sB, buf1, NN);
    // agg(mv) shared by rt1 and mv1
    k_segmax<<<gSeg, bSeg, 0, stream>>>(buf1, rowptr, esrc, bufA, NN);
    k_gemm<1><<<gGem, bGem, 0, stream>>>(bufA, buf1, rt1Wl, rt1Wr, rt1B, buf2, NN); // rt
    k_gemm<1><<<gGem, bGem, 0, stream>>>(bufA, buf1, mv1Wl, mv1Wr, mv1B, buf3, NN); // md
    // rt branch layer 2
    k_segmax<<<gSeg, bSeg, 0, stream>>>(buf2, rowptr, esrc, bufA, NN);
    k_gemm<1><<<gGem, bGem, 0, stream>>>(bufA, buf2, rt2Wl, rt2Wr, rt2B, buf1, NN); // rt2
    // md branch layer 2
    k_segmax<<<gSeg, bSeg, 0, stream>>>(buf3, rowptr, esrc, bufA, NN);
    k_gemm<1><<<gGem, bGem, 0, stream>>>(bufA, buf3, mv2Wl, mv2Wr, mv2B, buf2, NN); // md2
    // heads
    k_gemv<<<NN / 4, 256, 0, stream>>>(buf1, rt3W, rt3B, out, NN);
    k_gemv<<<NN / 4, 256, 0, stream>>>(buf2, mv3W, mv3B, out + NN, NN);
}

// Round 2
// 609.452 us; speedup vs baseline: 1.5191x; 1.5191x over previous
//
#include <hip/hip_runtime.h>
#include <hip/hip_bf16.h>
#include <math.h>

#define NN 50000
#define NE 800000
#define C  128

using f32x4  = __attribute__((ext_vector_type(4))) float;
using short8 = __attribute__((ext_vector_type(8))) short;

__device__ __forceinline__ unsigned short f2bf(float f) {
    unsigned int u = __float_as_uint(f);
    unsigned int r = u + 0x7FFFu + ((u >> 16) & 1u);
    return (unsigned short)(r >> 16);
}
__device__ __forceinline__ float bf2f(unsigned short h) {
    return __uint_as_float(((unsigned int)h) << 16);
}

// ---------------- CSR build ----------------

__global__ void k_zero(int* __restrict__ p, int n) {
    int i = blockIdx.x * blockDim.x + threadIdx.x;
    if (i < n) p[i] = 0;
}

__global__ void k_hist(const int* __restrict__ dst, int* __restrict__ deg, int nE) {
    int e = blockIdx.x * blockDim.x + threadIdx.x;
    if (e < nE) atomicAdd(&deg[dst[e]], 1);
}

__global__ void k_scan(const int* __restrict__ deg, int* __restrict__ rowptr, int n) {
    __shared__ int wsum[16];
    __shared__ int carry;
    int tid  = threadIdx.x;
    int lane = tid & 63, wid = tid >> 6;
    if (tid == 0) { rowptr[0] = 0; carry = 0; }
    __syncthreads();
    for (int base = 0; base < n; base += 1024) {
        int i = base + tid;
        int v = (i < n) ? deg[i] : 0;
        int incl = v;
        #pragma unroll
        for (int d = 1; d < 64; d <<= 1) {
            int t = __shfl_up(incl, d, 64);
            if (lane >= d) incl += t;
        }
        if (lane == 63) wsum[wid] = incl;
        __syncthreads();
        int wo = 0, total = 0;
        #pragma unroll
        for (int w = 0; w < 16; ++w) {
            int s = wsum[w];
            if (w < wid) wo += s;
            total += s;
        }
        if (i < n) rowptr[i + 1] = carry + wo + incl;
        __syncthreads();
        if (tid == 0) carry += total;
        __syncthreads();
    }
}

__global__ void k_fill(const int* __restrict__ src, const int* __restrict__ dst,
                       const int* __restrict__ rowptr, int* __restrict__ cursor,
                       int* __restrict__ esrc, int nE) {
    int e = blockIdx.x * blockDim.x + threadIdx.x;
    if (e < nE) {
        int d   = dst[e];
        int pos = rowptr[d] + atomicAdd(&cursor[d], 1);
        esrc[pos] = src[e];
    }
}

// ---------------- segment max ----------------
__global__ void k_segmax(const float* __restrict__ h, const int* __restrict__ rowptr,
                         const int* __restrict__ esrc, float* __restrict__ agg, int n) {
    int node = blockIdx.x * 2 + (threadIdx.x >> 7);
    int c    = threadIdx.x & 127;
    if (node >= n) return;
    int beg = rowptr[node], end = rowptr[node + 1];
    float m = -INFINITY;
    int i = beg;
    for (; i + 3 < end; i += 4) {
        int s0 = esrc[i], s1 = esrc[i + 1], s2 = esrc[i + 2], s3 = esrc[i + 3];
        float v0 = h[s0 * C + c], v1 = h[s1 * C + c];
        float v2 = h[s2 * C + c], v3 = h[s3 * C + c];
        m = fmaxf(m, fmaxf(fmaxf(v0, v1), fmaxf(v2, v3)));
    }
    for (; i < end; ++i) m = fmaxf(m, h[esrc[i] * C + c]);
    agg[node * C + c] = (end > beg) ? m : 0.0f;
}

// ---------------- weight pack: fragment-order bf16 hi/lo ----------------
// packed idx = ((t*8 + s)*64 + lane)*8 + j
//   n = t*16 + (lane&15) ; k = s*32 + (lane>>4)*8 + j ; Wcat[n][k] = k<128 ? Wl : Wr
__global__ void k_packw(const float* __restrict__ Wl, const float* __restrict__ Wr,
                        unsigned short* __restrict__ Wh, unsigned short* __restrict__ Wlo) {
    int idx = blockIdx.x * 256 + threadIdx.x;
    if (idx >= 128 * 256) return;
    int j = idx & 7, l = (idx >> 3) & 63, s = (idx >> 9) & 7, t = idx >> 12;
    int nrow = t * 16 + (l & 15);
    int k    = s * 32 + (l >> 4) * 8 + j;
    float v  = (k < 128) ? Wl[nrow * 128 + k] : Wr[nrow * 128 + (k - 128)];
    unsigned short h = f2bf(v);
    Wh[idx]  = h;
    Wlo[idx] = f2bf(v - bf2f(h));
}

// ---------------- split-bf16 MFMA SAGE gemm ----------------
// out[m, n] = relu( sum_k cat(A,X)[m,k] * Wcat[n,k] + b[n] ),  M tiles of 16/wave.
template<int RELU>
__global__ __launch_bounds__(256) void k_gemm_mfma(
        const float* __restrict__ A, const float* __restrict__ X,
        const unsigned short* __restrict__ Wh, const unsigned short* __restrict__ Wlo,
        const float* __restrict__ bias, float* __restrict__ out, int n) {
    int wave = threadIdx.x >> 6;
    int lane = threadIdx.x & 63;
    int rit  = lane & 15;        // row within m-tile (A), col within n-tile (B/D)
    int kgrp = lane >> 4;        // 0..3
    int m0   = blockIdx.x * 64 + wave * 16;

    f32x4 acc[8];
    #pragma unroll
    for (int t = 0; t < 8; ++t) acc[t] = (f32x4){0.f, 0.f, 0.f, 0.f};

    int arow = m0 + rit;
    if (arow > n - 1) arow = n - 1;     // clamp (stores are guarded)

    #pragma unroll
    for (int s = 0; s < 8; ++s) {
        int kk = s * 32 + kgrp * 8;     // global k of this lane's 8 elems
        const float* srcp = (kk < 128) ? (A + (size_t)arow * C + kk)
                                       : (X + (size_t)arow * C + (kk - 128));
        float4 v0 = *(const float4*)(srcp);
        float4 v1 = *(const float4*)(srcp + 4);
        float fv[8] = {v0.x, v0.y, v0.z, v0.w, v1.x, v1.y, v1.z, v1.w};
        short8 a_hi, a_lo;
        #pragma unroll
        for (int j = 0; j < 8; ++j) {
            unsigned short h = f2bf(fv[j]);
            a_hi[j] = (short)h;
            a_lo[j] = (short)f2bf(fv[j] - bf2f(h));
        }
        const unsigned short* wb = Wh  + ((size_t)(s * 64 + lane) << 3);
        const unsigned short* wl = Wlo + ((size_t)(s * 64 + lane) << 3);
        #pragma unroll
        for (int t = 0; t < 8; ++t) {
            short8 whf = *(const short8*)(wb + ((size_t)t << 12)); // t*8*64*8
            short8 wlf = *(const short8*)(wl + ((size_t)t << 12));
            acc[t] = __builtin_amdgcn_mfma_f32_16x16x32_bf16(a_hi, whf, acc[t], 0, 0, 0);
            acc[t] = __builtin_amdgcn_mfma_f32_16x16x32_bf16(a_lo, whf, acc[t], 0, 0, 0);
            acc[t] = __builtin_amdgcn_mfma_f32_16x16x32_bf16(a_hi, wlf, acc[t], 0, 0, 0);
        }
    }

    // C/D layout: col = lane&15, row = (lane>>4)*4 + j   [m89-verified]
    #pragma unroll
    for (int t = 0; t < 8; ++t) {
        int col = t * 16 + rit;
        float b = bias[col];
        #pragma unroll
        for (int j = 0; j < 4; ++j) {
            int rr = m0 + kgrp * 4 + j;
            if (rr < n) {
                float v = acc[t][j] + b;
                if (RELU) v = fmaxf(v, 0.f);
                out[(size_t)rr * C + col] = v;
            }
        }
    }
}

// ---------------- final 128->1 head ----------------
__global__ void k_gemv(const float* __restrict__ h, const float* __restrict__ w,
                       const float* __restrict__ b, float* __restrict__ out, int n) {
    int node = blockIdx.x * (blockDim.x >> 6) + (threadIdx.x >> 6);
    int lane = threadIdx.x & 63;
    if (node >= n) return;
    float s = h[node * C + lane] * w[lane] + h[node * C + 64 + lane] * w[64 + lane];
    #pragma unroll
    for (int d = 32; d > 0; d >>= 1) s += __shfl_down(s, d, 64);
    if (lane == 0) out[node] = s + b[0];
}

// ---------------- launch ----------------

extern "C" void kernel_launch(void* const* d_in, const int* in_sizes, int n_in,
                              void* d_out, int out_size, void* d_ws, size_t ws_size,
                              hipStream_t stream) {
    const float* x     = (const float*)d_in[0];
    const int*   ei    = (const int*)d_in[1];
    const int*   src   = ei;
    const int*   dstp  = ei + NE;
    const float* sWl   = (const float*)d_in[2];
    const float* sB    = (const float*)d_in[3];
    const float* sWr   = (const float*)d_in[4];
    const float* rt1Wl = (const float*)d_in[5];
    const float* rt1B  = (const float*)d_in[6];
    const float* rt1Wr = (const float*)d_in[7];
    const float* rt2Wl = (const float*)d_in[8];
    const float* rt2B  = (const float*)d_in[9];
    const float* rt2Wr = (const float*)d_in[10];
    const float* rt3W  = (const float*)d_in[11];
    const float* rt3B  = (const float*)d_in[12];
    const float* mv1Wl = (const float*)d_in[13];
    const float* mv1B  = (const float*)d_in[14];
    const float* mv1Wr = (const float*)d_in[15];
    const float* mv2Wl = (const float*)d_in[16];
    const float* mv2B  = (const float*)d_in[17];
    const float* mv2Wr = (const float*)d_in[18];
    const float* mv3W  = (const float*)d_in[19];
    const float* mv3B  = (const float*)d_in[20];
    float* out = (float*)d_out;

    char* ws = (char*)d_ws;
    int* rowptr = (int*)ws;                 // NN+1
    int* cursor = rowptr + (NN + 1);        // NN
    int* esrc   = cursor + NN;              // NE
    size_t off  = (((size_t)(NN + 1 + NN + NE) * 4) + 255) & ~(size_t)255;
    float* bufA = (float*)(ws + off);       // agg scratch
    float* buf1 = bufA + (size_t)NN * C;
    float* buf2 = buf1 + (size_t)NN * C;
    float* buf3 = buf2 + (size_t)NN * C;
    unsigned short* wpack = (unsigned short*)(buf3 + (size_t)NN * C); // 5*65536 ushorts
    unsigned short* pk[5][2];
    for (int L = 0; L < 5; ++L) {
        pk[L][0] = wpack + (size_t)L * 65536;          // hi
        pk[L][1] = wpack + (size_t)L * 65536 + 32768;  // lo
    }

    const int TB = 256;
    // weight packing (independent of CSR build)
    k_packw<<<128, 256, 0, stream>>>(sWl,   sWr,   pk[0][0], pk[0][1]);
    k_packw<<<128, 256, 0, stream>>>(rt1Wl, rt1Wr, pk[1][0], pk[1][1]);
    k_packw<<<128, 256, 0, stream>>>(rt2Wl, rt2Wr, pk[2][0], pk[2][1]);
    k_packw<<<128, 256, 0, stream>>>(mv1Wl, mv1Wr, pk[3][0], pk[3][1]);
    k_packw<<<128, 256, 0, stream>>>(mv2Wl, mv2Wr, pk[4][0], pk[4][1]);

    // CSR build
    k_zero<<<(NN + TB - 1) / TB, TB, 0, stream>>>(cursor, NN);
    k_hist<<<(NE + TB - 1) / TB, TB, 0, stream>>>(dstp, cursor, NE);
    k_scan<<<1, 1024, 0, stream>>>(cursor, rowptr, NN);
    k_zero<<<(NN + TB - 1) / TB, TB, 0, stream>>>(cursor, NN);
    k_fill<<<(NE + TB - 1) / TB, TB, 0, stream>>>(src, dstp, rowptr, cursor, esrc, NE);

    dim3 gSeg(NN / 2), bSeg(256);
    dim3 gGem((NN + 63) / 64), bGem(256);

    // shared layer: mv = relu(sage(x))
    k_segmax<<<gSeg, bSeg, 0, stream>>>(x, rowptr, esrc, bufA, NN);
    k_gemm_mfma<1><<<gGem, bGem, 0, stream>>>(bufA, x, pk[0][0], pk[0][1], sB, buf1, NN);
    // agg(mv) shared by rt1 and mv1
    k_segmax<<<gSeg, bSeg, 0, stream>>>(buf1, rowptr, esrc, bufA, NN);
    k_gemm_mfma<1><<<gGem, bGem, 0, stream>>>(bufA, buf1, pk[1][0], pk[1][1], rt1B, buf2, NN); // rt
    k_gemm_mfma<1><<<gGem, bGem, 0, stream>>>(bufA, buf1, pk[3][0], pk[3][1], mv1B, buf3, NN); // md
    // rt branch layer 2
    k_segmax<<<gSeg, bSeg, 0, stream>>>(buf2, rowptr, esrc, bufA, NN);
    k_gemm_mfma<1><<<gGem, bGem, 0, stream>>>(bufA, buf2, pk[2][0], pk[2][1], rt2B, buf1, NN); // rt2
    // md branch layer 2
    k_segmax<<<gSeg, bSeg, 0, stream>>>(buf3, rowptr, esrc, bufA, NN);
    k_gemm_mfma<1><<<gGem, bGem, 0, stream>>>(bufA, buf3, pk[4][0], pk[4][1], mv2B, buf2, NN); // md2
    // heads
    k_gemv<<<NN / 4, 256, 0, stream>>>(buf1, rt3W, rt3B, out, NN);
    k_gemv<<<NN / 4, 256, 0, stream>>>(buf2, mv3W, mv3B, out + NN, NN);
}